// Round 11
// baseline (297.510 us; speedup 1.0000x reference)
//
#include <hip/hip_runtime.h>
#include <hip/hip_bf16.h>

#define B_     8
#define CIN_   2
#define N_     512
#define C_     32
#define L_     64
#define LOUT_  61
#define BUF_   ((size_t)(8*32*512*64))   // 8,388,608 bf16 elements per scratch buffer

typedef __hip_bfloat16 bf16;
typedef unsigned short ushort_t;
typedef unsigned int u32;
typedef __attribute__((ext_vector_type(8))) unsigned short us8;
typedef __attribute__((ext_vector_type(8))) short bf16x8;
typedef __attribute__((ext_vector_type(4))) float f32x4;

static __device__ __forceinline__ float bits2f(ushort_t u) {
    return __uint_as_float(((unsigned)u) << 16);
}
static __device__ __forceinline__ ushort_t f2bits(float v) {   // RNE bf16 (finite inputs)
    unsigned u = __float_as_uint(v);
    return (ushort_t)((u + 0x7fffu + ((u >> 16) & 1u)) >> 16);
}

// async global->LDS, 16B per lane; LDS dest must be wave-uniform base + lane*16
static __device__ __forceinline__ void gload16(const ushort_t* g, ushort_t* l) {
    __builtin_amdgcn_global_load_lds(
        (const __attribute__((address_space(1))) unsigned int*)g,
        (__attribute__((address_space(3))) unsigned int*)l,
        16, 0, 0);
}

// swap value with quad-neighbor lane^1 (VALU DPP, no LDS traffic)
static __device__ __forceinline__ u32 swap1(u32 v) {
    return (u32)__builtin_amdgcn_update_dpp(0, (int)v, 0xB1, 0xF, 0xF, true);
}

// ---------------- K0: start 1x1 conv (2->32 ch). One octet of l per thread.
__global__ void k_start(const float* __restrict__ x,
                        const float* __restrict__ Wst,
                        const float* __restrict__ bst,
                        ushort_t* __restrict__ h) {
    int idx = blockIdx.x * 256 + threadIdx.x;      // octet id, 1,048,576 total
    int l0 = (idx & 7) * 8;
    int n  = (idx >> 3) & 511;
    int o  = (idx >> 12) & 31;
    int b  = idx >> 17;
    float w0 = Wst[o * 2], w1 = Wst[o * 2 + 1], bb = bst[o];
    int xbase = (b * CIN_ * N_ + n) * L_ + l0;
    float va[8], vb[8];
    *(float4*)&va[0] = *(const float4*)(x + xbase);
    *(float4*)&va[4] = *(const float4*)(x + xbase + 4);
    *(float4*)&vb[0] = *(const float4*)(x + xbase + N_ * L_);
    *(float4*)&vb[4] = *(const float4*)(x + xbase + N_ * L_ + 4);
    us8 r;
    #pragma unroll
    for (int k = 0; k < 8; ++k) r[k] = f2bits(bb + va[k] * w0 + vb[k] * w1);
    *(us8*)(h + (size_t)idx * 8) = r;
}

// ---------------- K_T: adjT[m][n] = bf16(adj[n][m]), one-shot 512x512 transpose
__global__ void k_transA(const float* __restrict__ adj, ushort_t* __restrict__ adjT) {
    __shared__ float buf[64][65];
    int ti = blockIdx.x & 7;        // n-tile
    int tj = blockIdx.x >> 3;       // m-tile
    int t = threadIdx.x;
    for (int r = 0; r < 16; ++r) {
        int e = t + 256 * r;
        int rl = e >> 6, cl = e & 63;
        buf[rl][cl] = adj[(size_t)(ti * 64 + rl) * 512 + tj * 64 + cl];
    }
    __syncthreads();
    for (int r = 0; r < 16; ++r) {
        int e = t + 256 * r;
        int ml = e >> 6, nl = e & 63;
        adjT[(size_t)(tj * 64 + ml) * 512 + ti * 64 + nl] = f2bits(buf[nl][ml]);
    }
}

// ---------------- K_SQ: adj2T = adjT x adjT  (= (A^2)^T), bf16 MFMA, one-shot
__global__ __launch_bounds__(256, 2) void k_sq(const ushort_t* __restrict__ adjT,
                                               ushort_t* __restrict__ adj2T) {
    __shared__ __align__(16) ushort_t lds2[8192];   // As 4096 | Bs 4096; Ys aliases
    ushort_t* As = lds2;
    ushort_t* Bs = lds2 + 4096;
    int mt = blockIdx.x & 7, nc = blockIdx.x >> 3;
    int t = threadIdx.x, lane = t & 63, w = t >> 6;
    int la = lane & 15, q = lane >> 4;
    f32x4 acc[4];
    #pragma unroll
    for (int mi = 0; mi < 4; ++mi) acc[mi] = (f32x4)0.f;
    for (int p0 = 0; p0 < 512; p0 += 64) {
        __syncthreads();
        #pragma unroll
        for (int r = 0; r < 2; ++r) {
            int e = t + 256 * r, ml = e >> 3, oct = e & 7;
            int sw = ((oct + (ml >> 3)) & 7) << 3;
            *(us8*)(As + ml * 64 + sw) =
                *(const us8*)(adjT + (size_t)(mt * 64 + ml) * 512 + p0 + oct * 8);
            *(us8*)(Bs + ml * 64 + sw) =
                *(const us8*)(adjT + (size_t)(p0 + ml) * 512 + nc * 64 + oct * 8);
        }
        __syncthreads();
        #pragma unroll
        for (int ks = 0; ks < 2; ++ks) {
            bf16x8 a[4];
            #pragma unroll
            for (int mi = 0; mi < 4; ++mi) {
                int m = mi * 16 + la;
                int bl = (ks * 4 + q + (m >> 3)) & 7;
                a[mi] = *(const bf16x8*)(As + m * 64 + bl * 8);
            }
            bf16x8 bv;
            {
                int n = w * 16 + la;
                int rot = ((n >> 3) + ks * 4 + q) & 7;
                int col = rot * 8 + (n & 7);
                const ushort_t* p = Bs + (ks * 32 + q * 8) * 64 + col;
                #pragma unroll
                for (int j = 0; j < 8; ++j) bv[j] = (short)p[j * 64];
            }
            #pragma unroll
            for (int mi = 0; mi < 4; ++mi)
                acc[mi] = __builtin_amdgcn_mfma_f32_16x16x32_bf16(a[mi], bv, acc[mi], 0, 0, 0);
        }
    }
    __syncthreads();
    ushort_t* Ys = lds2;   // [64][72]
    #pragma unroll
    for (int mi = 0; mi < 4; ++mi)
        #pragma unroll
        for (int r = 0; r < 4; ++r)
            Ys[(mi * 16 + q * 4 + r) * 72 + w * 16 + la] = f2bits(acc[mi][r]);
    __syncthreads();
    #pragma unroll
    for (int r = 0; r < 2; ++r) {
        int e = t + 256 * r, ml = e >> 3, oct = e & 7;
        us8 v = *(const us8*)(Ys + ml * 72 + oct * 8);
        *(us8*)(adj2T + (size_t)(mt * 64 + ml) * 512 + nc * 64 + oct * 8) = v;
    }
}

// ---------------- K1: FUSED MFMA gated conv + skip conv (+ optional output BN)
// v5: commutation fusion — when doH, epilogue also emits H0=W1*G, H1=W2*G, H2=W3*G
//     (three skip-style 32x32 MFMA passes over the resident G tile) so the gc
//     kernel is deleted; G itself is never written (only H0..H2).
__global__ __launch_bounds__(256, 4) void k_gs_mfma(
        const ushort_t* __restrict__ h,
        const float* __restrict__ Wf, const float* __restrict__ bfp,
        const float* __restrict__ Wg, const float* __restrict__ bgp,
        const float* __restrict__ Wsk, const float* __restrict__ bsk,
        const float* __restrict__ Wgc,
        ushort_t* __restrict__ H0, ushort_t* __restrict__ H1, ushort_t* __restrict__ H2,
        float* __restrict__ out,
        int off, int mode, int doH,
        const float* __restrict__ og, const float* __restrict__ obb) {
    // Hs [64][64] rot 4096u | Asf 32x72 2304u | Asg 2304u | As2 32x40 1280u | AwH 3x32x40 3840u
    // Hst (H staging [64][72]) reuses Asf+Asg (4608u); St float[128][36]=9216u overlays base.
    __shared__ __align__(16) ushort_t lds[13824];   // 27648 B
    ushort_t* Hs  = lds;           // [64 rows][64], slot = ((l>>3)+row+(row>>5))&7
    ushort_t* Asf = lds + 4096;
    ushort_t* Asg = lds + 6400;
    ushort_t* As2 = lds + 8704;
    ushort_t* AwH = lds + 9984;    // 3 x [32][40]
    ushort_t* Hst = lds + 4096;    // [64][72], overlays Asf+Asg (dead after frag loads)
    __shared__ float bfv[32], bgv[32], bsv[32];
    int t = threadIdx.x;
    int b = blockIdx.x >> 8, n0 = (blockIdx.x & 255) * 2;
    int lane = t & 63, w = t >> 6;
    int ng = w & 1, cg = w >> 1;
    int la = lane & 15, q = lane >> 4;

    // --- async stage H tile (rotated layout via pre-rotated global octet)
    const ushort_t* hb = h + (size_t)(b * 32) * 512 * 64;
    #pragma unroll
    for (int r = 0; r < 2; ++r) {
        int e = t + 256 * r;               // 512 16B-units
        int row = e >> 3, s = e & 7;
        int og_ = ((s - row - (row >> 5)) & 7) * 8;
        gload16(hb + ((size_t)(row >> 1) * 512 + n0 + (row & 1)) * 64 + og_,
                Hs + (size_t)e * 8);
    }
    // --- weights (reg-staged: fp32->bf16 + layout transform)
    {
        int o = t >> 3, k8 = (t & 7) * 8;
        us8 vf, vg;
        #pragma unroll
        for (int i = 0; i < 8; ++i) {
            int k = k8 + i, c = k & 31, tap = k >> 5;
            vf[i] = f2bits(Wf[o * 64 + c * 2 + tap]);
            vg[i] = f2bits(Wg[o * 64 + c * 2 + tap]);
        }
        *(us8*)(Asf + o * 72 + k8) = vf;
        *(us8*)(Asg + o * 72 + k8) = vg;
        if (k8 < 32) {
            us8 vs;
            #pragma unroll
            for (int i = 0; i < 8; ++i) vs[i] = f2bits(Wsk[o * 32 + k8 + i]);
            *(us8*)(As2 + o * 40 + k8) = vs;
        }
        if (t < 32) { bfv[t] = bfp[t]; bgv[t] = bgp[t]; bsv[t] = bsk[t]; }
    }
    if (doH) {                             // stage Wgc -> three bf16 [32][40] tiles
        for (int e = t; e < 384; e += 256) {
            int j = e >> 7, rem = e & 127, o = rem >> 2, g = rem & 3;
            us8 v;
            #pragma unroll
            for (int i = 0; i < 8; ++i) v[i] = f2bits(Wgc[o * 96 + j * 32 + g * 8 + i]);
            *(us8*)(AwH + j * 1280 + o * 40 + g * 8) = v;
        }
    }
    // --- T14: prefetch the out-RMW read; consumed at the very end
    float4 oldv[4];
    #pragma unroll
    for (int i = 0; i < 4; ++i) oldv[i] = make_float4(0.f, 0.f, 0.f, 0.f);
    {
        int col = t >> 1, o0 = (t & 1) * 16;
        int nr = col >> 6, l = col & 63;
        if (mode != 0 && l < LOUT_) {
            const float* po = out + ((size_t)(b * LOUT_ + l) * 512 + n0 + nr) * 32 + o0;
            #pragma unroll
            for (int i = 0; i < 4; ++i) oldv[i] = *(const float4*)(po + i * 4);
        }
    }
    __syncthreads();   // drains gload16 (vmcnt) + weight ds_writes

    bf16x8 af[2][2], ag[2][2];
    #pragma unroll
    for (int mt = 0; mt < 2; ++mt)
        #pragma unroll
        for (int ks = 0; ks < 2; ++ks) {
            af[mt][ks] = *(const bf16x8*)(Asf + (mt * 16 + la) * 72 + ks * 32 + q * 8);
            ag[mt][ks] = *(const bf16x8*)(Asg + (mt * 16 + la) * 72 + ks * 32 + q * 8);
        }
    bf16x8 a2[2];
    a2[0] = *(const bf16x8*)(As2 + la * 40 + q * 8);
    a2[1] = *(const bf16x8*)(As2 + (16 + la) * 40 + q * 8);

    f32x4 fa[2][2], ga[2][2];
    #pragma unroll
    for (int mt = 0; mt < 2; ++mt)
        #pragma unroll
        for (int cl = 0; cl < 2; ++cl) { fa[mt][cl] = (f32x4)0.f; ga[mt][cl] = (f32x4)0.f; }
    #pragma unroll
    for (int cl = 0; cl < 2; ++cl) {
        int ct = cg * 2 + cl;
        #pragma unroll
        for (int ks = 0; ks < 2; ++ks) {
            int le = ct * 16 + la + ks;
            bf16x8 bv;
            #pragma unroll
            for (int j = 0; j < 8; ++j) {
                int row = (q * 8 + j) * 2 + ng;
                int slot = ((le >> 3) + row + (row >> 5)) & 7;
                bv[j] = (le < 64) ? (short)Hs[row * 64 + (slot & 7) * 8 + (le & 7)] : (short)0;
            }
            #pragma unroll
            for (int mt = 0; mt < 2; ++mt) {
                fa[mt][cl] = __builtin_amdgcn_mfma_f32_16x16x32_bf16(af[mt][ks], bv, fa[mt][cl], 0, 0, 0);
                ga[mt][cl] = __builtin_amdgcn_mfma_f32_16x16x32_bf16(ag[mt][ks], bv, ga[mt][cl], 0, 0, 0);
            }
        }
    }
    __syncthreads();   // all H reads done before act overwrites (col 32 crosses cg waves)

    #pragma unroll
    for (int mt = 0; mt < 2; ++mt)
        #pragma unroll
        for (int cl = 0; cl < 2; ++cl)
            #pragma unroll
            for (int r = 0; r < 4; ++r) {
                int o = mt * 16 + q * 4 + r;
                float fv = fa[mt][cl][r] + bfv[o];
                float gv = ga[mt][cl][r] + bgv[o];
                float ef = __expf(2.f * fv);
                float act = (1.f - 2.f / (ef + 1.f)) * (1.f / (1.f + __expf(-gv)));
                int l = (cg * 2 + cl) * 16 + la;
                int row = o * 2 + ng;
                int slot = ((l >> 3) + row + (row >> 5)) & 7;
                Hs[row * 64 + slot * 8 + (l & 7)] = f2bits(act);
            }
    __syncthreads();   // gated tile (G) complete

    // --- skip MFMA (reads Hs)
    f32x4 sa[2][2];
    #pragma unroll
    for (int mt = 0; mt < 2; ++mt)
        #pragma unroll
        for (int cl = 0; cl < 2; ++cl) sa[mt][cl] = (f32x4)0.f;
    #pragma unroll
    for (int cl = 0; cl < 2; ++cl) {
        int le = (cg * 2 + cl) * 16 + la + off;
        bf16x8 bv;
        #pragma unroll
        for (int j = 0; j < 8; ++j) {
            int row = (q * 8 + j) * 2 + ng;
            int slot = ((le >> 3) + row + (row >> 5)) & 7;
            bv[j] = (le < 64) ? (short)Hs[row * 64 + (slot & 7) * 8 + (le & 7)] : (short)0;
        }
        sa[0][cl] = __builtin_amdgcn_mfma_f32_16x16x32_bf16(a2[0], bv, sa[0][cl], 0, 0, 0);
        sa[1][cl] = __builtin_amdgcn_mfma_f32_16x16x32_bf16(a2[1], bv, sa[1][cl], 0, 0, 0);
    }

    // --- H passes: H_j = Wj * G (j=0,1,2), reuse off=0 G fragments
    if (doH) {
        bf16x8 bv0[2];
        #pragma unroll
        for (int cl = 0; cl < 2; ++cl) {
            int le = (cg * 2 + cl) * 16 + la;
            #pragma unroll
            for (int j = 0; j < 8; ++j) {
                int row = (q * 8 + j) * 2 + ng;
                int slot = ((le >> 3) + row + (row >> 5)) & 7;
                bv0[cl][j] = (short)Hs[row * 64 + slot * 8 + (le & 7)];
            }
        }
        ushort_t* dsts[3] = {H0, H1, H2};
        #pragma unroll
        for (int j = 0; j < 3; ++j) {
            bf16x8 aH0 = *(const bf16x8*)(AwH + j * 1280 + la * 40 + q * 8);
            bf16x8 aH1 = *(const bf16x8*)(AwH + j * 1280 + (16 + la) * 40 + q * 8);
            f32x4 sh[2][2];
            #pragma unroll
            for (int mt = 0; mt < 2; ++mt)
                #pragma unroll
                for (int cl = 0; cl < 2; ++cl) sh[mt][cl] = (f32x4)0.f;
            #pragma unroll
            for (int cl = 0; cl < 2; ++cl) {
                sh[0][cl] = __builtin_amdgcn_mfma_f32_16x16x32_bf16(aH0, bv0[cl], sh[0][cl], 0, 0, 0);
                sh[1][cl] = __builtin_amdgcn_mfma_f32_16x16x32_bf16(aH1, bv0[cl], sh[1][cl], 0, 0, 0);
            }
            // stage to Hst [64 rows=o*2+ng][72] then coalesced store
            #pragma unroll
            for (int mt = 0; mt < 2; ++mt)
                #pragma unroll
                for (int cl = 0; cl < 2; ++cl)
                    #pragma unroll
                    for (int r = 0; r < 4; ++r) {
                        int o = mt * 16 + q * 4 + r;
                        int l = (cg * 2 + cl) * 16 + la;
                        Hst[(o * 2 + ng) * 72 + l] = f2bits(sh[mt][cl][r]);
                    }
            __syncthreads();
            ushort_t* dst = dsts[j];
            #pragma unroll
            for (int r = 0; r < 2; ++r) {
                int e = t + 256 * r;
                int row = e >> 3, oct = e & 7;
                us8 v = *(const us8*)(Hst + row * 72 + oct * 8);
                *(us8*)(dst + ((size_t)(b * 32 + (row >> 1)) * 512 + n0 + (row & 1)) * 64 + oct * 8) = v;
            }
            __syncthreads();
        }
    }
    __syncthreads();   // Hs/As2/Hst dead -> St overlays lds

    float* St = (float*)lds;               // [128 cols][36]; col = ng*64 + l
    const float rbn = rsqrtf(1.f + 1e-5f);
    #pragma unroll
    for (int mt = 0; mt < 2; ++mt)
        #pragma unroll
        for (int cl = 0; cl < 2; ++cl) {
            int col = ng * 64 + (cg * 2 + cl) * 16 + la;
            int ob = mt * 16 + q * 4;
            float4 sv = make_float4(sa[mt][cl][0] + bsv[ob],
                                    sa[mt][cl][1] + bsv[ob + 1],
                                    sa[mt][cl][2] + bsv[ob + 2],
                                    sa[mt][cl][3] + bsv[ob + 3]);
            *(float4*)(St + col * 36 + ob) = sv;
        }
    __syncthreads();
    {
        int col = t >> 1, o0 = (t & 1) * 16;
        int nr = col >> 6, l = col & 63;
        if (l < LOUT_) {
            float* po = out + ((size_t)(b * LOUT_ + l) * 512 + n0 + nr) * 32 + o0;
            #pragma unroll
            for (int i = 0; i < 4; ++i) {
                float4 s = *(float4*)(St + col * 36 + o0 + i * 4);
                if (mode == 0) {
                    *(float4*)(po + i * 4) = s;
                } else {
                    float4 vv = make_float4(oldv[i].x + s.x, oldv[i].y + s.y,
                                            oldv[i].z + s.z, oldv[i].w + s.w);
                    if (mode == 2) {
                        int ob = o0 + i * 4;
                        vv.x = vv.x * (og[ob] * rbn) + obb[ob];
                        vv.y = vv.y * (og[ob + 1] * rbn) + obb[ob + 1];
                        vv.z = vv.z * (og[ob + 2] * rbn) + obb[ob + 2];
                        vv.w = vv.w * (og[ob + 3] * rbn) + obb[ob + 3];
                    }
                    *(float4*)(po + i * 4) = vv;
                }
            }
        }
    }
}

// ---------------- K3: FUSED diffusion + gc epilogue (replaces diffuse2 AND gc3)
// v2 epilogue: acc -> f32 LDS transpose at stride 73 (coprime 32 -> uniform banks;
//     the old [64][64] staging made every scalar read 8-way: row*64 = 0 mod 32
//     dwords, q absent from bank index -> 4.78M conflicts). H0/hres now read
//     COALESCED (us8) from global in the output layout; combine in f32 (same op
//     order as before -> bit-identical); write. No staging gloads, 2 fewer barriers.
__global__ __launch_bounds__(256, 3) void k_diffgc(
        ushort_t* __restrict__ H0, const ushort_t* __restrict__ H1,
        const ushort_t* __restrict__ H2, const ushort_t* __restrict__ hres,
        const ushort_t* __restrict__ adjT, const ushort_t* __restrict__ adj2T,
        const float* __restrict__ bgc, const float* __restrict__ gg,
        const float* __restrict__ gb, const float* __restrict__ bg2,
        const float* __restrict__ bb2) {
    // phase buf: As1 2048 | As2 2048 | B1s 4096 | B2s 4096 = 12288 u; dbuf 24576 u (48KB)
    // epilogue: YsF float[2][64][73] = 37376 B overlays lds.
    __shared__ __align__(16) ushort_t lds[24576];
    __shared__ float prm[5][32];
    int cp = blockIdx.x & 15;          // output-channel pair
    int mt = (blockIdx.x >> 4) & 7;
    int b  = blockIdx.x >> 7;
    int t  = threadIdx.x;
    int lane = t & 63, w = t >> 6;
    int c_loc = w & 1, lh = w >> 1;
    int m0 = mt * 64;
    int la = lane & 15, q = lane >> 4;
    int p_ = la & 1;
    u32 sel = p_ ? 0x07060302u : 0x05040100u;
    const ushort_t* B1b = H1 + (size_t)(b * 32 + cp * 2) * 512 * 64;
    const ushort_t* B2b = H2 + (size_t)(b * 32 + cp * 2) * 512 * 64;
    if (t < 32) {
        prm[0][t] = bgc[t]; prm[1][t] = gg[t]; prm[2][t] = gb[t];
        prm[3][t] = bg2[t]; prm[4][t] = bb2[t];
    }
    f32x4 acc1[4][2], acc2[4][2];
    #pragma unroll
    for (int mi = 0; mi < 4; ++mi)
        #pragma unroll
        for (int li = 0; li < 2; ++li) { acc1[mi][li] = (f32x4)0.f; acc2[mi][li] = (f32x4)0.f; }

    union U { u32 u[4]; bf16x8 v; };

    auto STAGE = [&](int n0, ushort_t* bb) {
        ushort_t* As1b = bb;            // 2048 u
        ushort_t* As2b = bb + 2048;
        ushort_t* B1sb = bb + 4096;     // 4096 u each
        ushort_t* B2sb = bb + 8192;
        {   // A tiles: linear (64B row stride is naturally bank-uniform)
            int ml = t >> 2, g = t & 3;
            gload16(adjT  + (size_t)(m0 + ml) * 512 + n0 + g * 8, As1b + (size_t)t * 8);
            gload16(adj2T + (size_t)(m0 + ml) * 512 + n0 + g * 8, As2b + (size_t)t * 8);
        }
        #pragma unroll
        for (int r = 0; r < 2; ++r) {   // B tiles: per-row rotated
            int e = t + 256 * r;
            int cl = e >> 8, nl = (e >> 3) & 31, s = e & 7;
            int og = ((s - nl - (nl >> 3)) & 7) * 8;
            gload16(B1b + ((size_t)cl * 512 + n0 + nl) * 64 + og, B1sb + (size_t)e * 8);
            gload16(B2b + ((size_t)cl * 512 + n0 + nl) * 64 + og, B2sb + (size_t)e * 8);
        }
    };

    STAGE(0, lds);
    __syncthreads();

    for (int it = 0; it < 16; ++it) {
        ushort_t* cur = lds + (it & 1) * 12288;
        if (it < 15) STAGE((it + 1) * 32, lds + ((it + 1) & 1) * 12288);
        ushort_t* As1 = cur;
        ushort_t* As2 = cur + 2048;
        const ushort_t* xc1 = cur + 4096 + c_loc * 2048;
        const ushort_t* xc2 = cur + 8192 + c_loc * 2048;
        bf16x8 a1[4], a2v[4];
        #pragma unroll
        for (int mi = 0; mi < 4; ++mi) {
            int m = mi * 16 + la;
            a1[mi]  = *(const bf16x8*)(As1 + m * 32 + q * 8);
            a2v[mi] = *(const bf16x8*)(As2 + m * 32 + q * 8);
        }
        bf16x8 bb1[2], bb2[2];
        #pragma unroll
        for (int li = 0; li < 2; ++li) {
            int l2 = lh * 32 + li * 16 + (la & ~1);
            int r0 = q * 8 + p_ * 4;
            int brot = ((l2 >> 3) + p_ * 4 + q) & 7;
            #pragma unroll
            for (int src = 0; src < 2; ++src) {
                const ushort_t* xc = src ? xc2 : xc1;
                u32 o0 = *(const u32*)(xc + (r0 + 0) * 64 + (((brot + 0) & 7) << 3) + (l2 & 7));
                u32 o1 = *(const u32*)(xc + (r0 + 1) * 64 + (((brot + 1) & 7) << 3) + (l2 & 7));
                u32 o2 = *(const u32*)(xc + (r0 + 2) * 64 + (((brot + 2) & 7) << 3) + (l2 & 7));
                u32 o3 = *(const u32*)(xc + (r0 + 3) * 64 + (((brot + 3) & 7) << 3) + (l2 & 7));
                u32 s0 = swap1(o0), s1 = swap1(o1), s2 = swap1(o2), s3 = swap1(o3);
                u32 lo0 = p_ ? s0 : o0, lo1 = p_ ? s1 : o1;
                u32 lo2 = p_ ? s2 : o2, lo3 = p_ ? s3 : o3;
                u32 hi0 = p_ ? o0 : s0, hi1 = p_ ? o1 : s1;
                u32 hi2 = p_ ? o2 : s2, hi3 = p_ ? o3 : s3;
                U u;
                u.u[0] = __builtin_amdgcn_perm(lo1, lo0, sel);
                u.u[1] = __builtin_amdgcn_perm(lo3, lo2, sel);
                u.u[2] = __builtin_amdgcn_perm(hi1, hi0, sel);
                u.u[3] = __builtin_amdgcn_perm(hi3, hi2, sel);
                if (src) bb2[li] = u.v; else bb1[li] = u.v;
            }
        }
        #pragma unroll
        for (int mi = 0; mi < 4; ++mi)
            #pragma unroll
            for (int li = 0; li < 2; ++li) {
                acc1[mi][li] = __builtin_amdgcn_mfma_f32_16x16x32_bf16(a1[mi],  bb1[li], acc1[mi][li], 0, 0, 0);
                acc2[mi][li] = __builtin_amdgcn_mfma_f32_16x16x32_bf16(a2v[mi], bb2[li], acc2[mi][li], 0, 0, 0);
            }
        __syncthreads();
    }

    // --- epilogue v2: f32 transpose at stride 73 (uniform banks), then coalesced
    //     global H0/hres reads in the OUTPUT layout; combine; write over H0.
    float* YsF = (float*)lds;        // [2][64][73] f32 = 37376 B
    #pragma unroll
    for (int mi = 0; mi < 4; ++mi)
        #pragma unroll
        for (int li = 0; li < 2; ++li)
            #pragma unroll
            for (int r = 0; r < 4; ++r) {
                int row = mi * 16 + q * 4 + r;          // m
                int col = lh * 32 + li * 16 + la;       // l
                YsF[c_loc * 4672 + row * 73 + col] = acc1[mi][li][r] + acc2[mi][li][r];
            }
    __syncthreads();

    const float rbn = rsqrtf(1.f + 1e-5f);
    {
        int c = t >> 7, mrem = t & 127;
        int m = mrem >> 1, lq = mrem & 1;
        int op = cp * 2 + c;
        float b0 = prm[0][op], g1 = prm[1][op] * rbn, b1 = prm[2][op];
        float g2 = prm[3][op] * rbn, b2 = prm[4][op];
        size_t gbase = ((size_t)(b * 32 + cp * 2 + c) * 512 + m0 + m) * 64;
        const float* yrow = YsF + c * 4672 + m * 73;
        #pragma unroll
        for (int r = 0; r < 4; ++r) {
            int l0 = lq * 32 + r * 8;
            us8 h0 = *(const us8*)(H0 + gbase + l0);
            us8 hr = *(const us8*)(hres + gbase + l0);
            ushort_t hx = (l0 + 8 < 64) ? hres[gbase + l0 + 8] : (ushort_t)0;
            us8 outv;
            #pragma unroll
            for (int k = 0; k < 8; ++k) {
                int l = l0 + k;
                float v = yrow[l] + bits2f(h0[k]) + b0;
                v = v * g1 + b1;
                float res = (l < 63) ? bits2f((k < 7) ? hr[k + 1] : hx) : 0.f;
                v = (v + res) * g2 + b2;
                outv[k] = f2bits(v);
            }
            *(us8*)(H0 + gbase + l0) = outv;
        }
    }
}

extern "C" void kernel_launch(void* const* d_in, const int* in_sizes, int n_in,
                              void* d_out, int out_size, void* d_ws, size_t ws_size,
                              hipStream_t stream) {
    const float* x      = (const float*)d_in[0];
    const float* adj    = (const float*)d_in[1];
    const float* Wstart = (const float*)d_in[2];
    const float* bstart = (const float*)d_in[3];
    const float* Wf     = (const float*)d_in[4];
    const float* bf_    = (const float*)d_in[5];
    const float* Wg     = (const float*)d_in[6];
    const float* bg     = (const float*)d_in[7];
    const float* Wskip  = (const float*)d_in[8];
    const float* bskip  = (const float*)d_in[9];
    const float* Wgc    = (const float*)d_in[10];
    const float* bgc    = (const float*)d_in[11];
    const float* gcbn_g = (const float*)d_in[12];
    const float* gcbn_b = (const float*)d_in[13];
    const float* bn_g   = (const float*)d_in[14];
    const float* bn_b   = (const float*)d_in[15];
    const float* obn_g  = (const float*)d_in[16];
    const float* obn_b  = (const float*)d_in[17];
    float* out = (float*)d_out;

    // 4 bf16 scratch buffers (64 MiB) + adjT + adj2T (512 KiB each)
    ushort_t* P0    = (ushort_t*)d_ws;
    ushort_t* P1    = P0 + BUF_;
    ushort_t* P2    = P1 + BUF_;
    ushort_t* P3    = P2 + BUF_;
    ushort_t* adjT  = P3 + BUF_;
    ushort_t* adj2T = adjT + 512 * 512;

    k_transA<<<64, 256, 0, stream>>>(adj, adjT);
    k_sq<<<64, 256, 0, stream>>>(adjT, adj2T);
    k_start<<<4096, 256, 0, stream>>>(x, Wstart, bstart, P0);

    ushort_t* h   = P0;
    ushort_t* alt = P1;
    for (int i = 0; i < 3; ++i) {
        int mode = (i == 0) ? 0 : ((i == 2) ? 2 : 1);
        k_gs_mfma<<<2048, 256, 0, stream>>>(h, Wf + i * 2048, bf_ + i * 32,
                                            Wg + i * 2048, bg + i * 32,
                                            Wskip + i * 1024, bskip + i * 32,
                                            Wgc + i * 3072,
                                            alt, P2, P3, out, 2 - i, mode, (i < 2) ? 1 : 0,
                                            obn_g, obn_b);
        if (i == 2) break;
        k_diffgc<<<1024, 256, 0, stream>>>(alt, P2, P3, h, adjT, adj2T,
                                           bgc + i * 32, gcbn_g + i * 32, gcbn_b + i * 32,
                                           bn_g + i * 32, bn_b + i * 32);
        ushort_t* nh = alt; alt = h; h = nh;   // h_next lives in alt; old h freed for next H0
    }
}

// Round 12
// 291.594 us; speedup vs baseline: 1.0203x; 1.0203x over previous
//
#include <hip/hip_runtime.h>
#include <hip/hip_bf16.h>

#define B_     8
#define CIN_   2
#define N_     512
#define C_     32
#define L_     64
#define LOUT_  61
#define BUF_   ((size_t)(8*32*512*64))   // 8,388,608 bf16 elements per scratch buffer

typedef __hip_bfloat16 bf16;
typedef unsigned short ushort_t;
typedef unsigned int u32;
typedef __attribute__((ext_vector_type(8))) unsigned short us8;
typedef __attribute__((ext_vector_type(8))) short bf16x8;
typedef __attribute__((ext_vector_type(4))) float f32x4;

static __device__ __forceinline__ float bits2f(ushort_t u) {
    return __uint_as_float(((unsigned)u) << 16);
}
static __device__ __forceinline__ ushort_t f2bits(float v) {   // RNE bf16 (finite inputs)
    unsigned u = __float_as_uint(v);
    return (ushort_t)((u + 0x7fffu + ((u >> 16) & 1u)) >> 16);
}

// async global->LDS, 16B per lane; LDS dest must be wave-uniform base + lane*16
static __device__ __forceinline__ void gload16(const ushort_t* g, ushort_t* l) {
    __builtin_amdgcn_global_load_lds(
        (const __attribute__((address_space(1))) unsigned int*)g,
        (__attribute__((address_space(3))) unsigned int*)l,
        16, 0, 0);
}

// swap value with quad-neighbor lane^1 (VALU DPP, no LDS traffic)
static __device__ __forceinline__ u32 swap1(u32 v) {
    return (u32)__builtin_amdgcn_update_dpp(0, (int)v, 0xB1, 0xF, 0xF, true);
}

// ---------------- K0: start 1x1 conv (2->32 ch). One octet of l per thread.
__global__ void k_start(const float* __restrict__ x,
                        const float* __restrict__ Wst,
                        const float* __restrict__ bst,
                        ushort_t* __restrict__ h) {
    int idx = blockIdx.x * 256 + threadIdx.x;      // octet id, 1,048,576 total
    int l0 = (idx & 7) * 8;
    int n  = (idx >> 3) & 511;
    int o  = (idx >> 12) & 31;
    int b  = idx >> 17;
    float w0 = Wst[o * 2], w1 = Wst[o * 2 + 1], bb = bst[o];
    int xbase = (b * CIN_ * N_ + n) * L_ + l0;
    float va[8], vb[8];
    *(float4*)&va[0] = *(const float4*)(x + xbase);
    *(float4*)&va[4] = *(const float4*)(x + xbase + 4);
    *(float4*)&vb[0] = *(const float4*)(x + xbase + N_ * L_);
    *(float4*)&vb[4] = *(const float4*)(x + xbase + N_ * L_ + 4);
    us8 r;
    #pragma unroll
    for (int k = 0; k < 8; ++k) r[k] = f2bits(bb + va[k] * w0 + vb[k] * w1);
    *(us8*)(h + (size_t)idx * 8) = r;
}

// ---------------- K_T: adjT[m][n] = bf16(adj[n][m]), one-shot 512x512 transpose
__global__ void k_transA(const float* __restrict__ adj, ushort_t* __restrict__ adjT) {
    __shared__ float buf[64][65];
    int ti = blockIdx.x & 7;        // n-tile
    int tj = blockIdx.x >> 3;       // m-tile
    int t = threadIdx.x;
    for (int r = 0; r < 16; ++r) {
        int e = t + 256 * r;
        int rl = e >> 6, cl = e & 63;
        buf[rl][cl] = adj[(size_t)(ti * 64 + rl) * 512 + tj * 64 + cl];
    }
    __syncthreads();
    for (int r = 0; r < 16; ++r) {
        int e = t + 256 * r;
        int ml = e >> 6, nl = e & 63;
        adjT[(size_t)(tj * 64 + ml) * 512 + ti * 64 + nl] = f2bits(buf[nl][ml]);
    }
}

// ---------------- K_SQ: adj2T = adjT x adjT  (= (A^2)^T), bf16 MFMA, one-shot
__global__ __launch_bounds__(256, 2) void k_sq(const ushort_t* __restrict__ adjT,
                                               ushort_t* __restrict__ adj2T) {
    __shared__ __align__(16) ushort_t lds2[8192];   // As 4096 | Bs 4096; Ys aliases
    ushort_t* As = lds2;
    ushort_t* Bs = lds2 + 4096;
    int mt = blockIdx.x & 7, nc = blockIdx.x >> 3;
    int t = threadIdx.x, lane = t & 63, w = t >> 6;
    int la = lane & 15, q = lane >> 4;
    f32x4 acc[4];
    #pragma unroll
    for (int mi = 0; mi < 4; ++mi) acc[mi] = (f32x4)0.f;
    for (int p0 = 0; p0 < 512; p0 += 64) {
        __syncthreads();
        #pragma unroll
        for (int r = 0; r < 2; ++r) {
            int e = t + 256 * r, ml = e >> 3, oct = e & 7;
            int sw = ((oct + (ml >> 3)) & 7) << 3;
            *(us8*)(As + ml * 64 + sw) =
                *(const us8*)(adjT + (size_t)(mt * 64 + ml) * 512 + p0 + oct * 8);
            *(us8*)(Bs + ml * 64 + sw) =
                *(const us8*)(adjT + (size_t)(p0 + ml) * 512 + nc * 64 + oct * 8);
        }
        __syncthreads();
        #pragma unroll
        for (int ks = 0; ks < 2; ++ks) {
            bf16x8 a[4];
            #pragma unroll
            for (int mi = 0; mi < 4; ++mi) {
                int m = mi * 16 + la;
                int bl = (ks * 4 + q + (m >> 3)) & 7;
                a[mi] = *(const bf16x8*)(As + m * 64 + bl * 8);
            }
            bf16x8 bv;
            {
                int n = w * 16 + la;
                int rot = ((n >> 3) + ks * 4 + q) & 7;
                int col = rot * 8 + (n & 7);
                const ushort_t* p = Bs + (ks * 32 + q * 8) * 64 + col;
                #pragma unroll
                for (int j = 0; j < 8; ++j) bv[j] = (short)p[j * 64];
            }
            #pragma unroll
            for (int mi = 0; mi < 4; ++mi)
                acc[mi] = __builtin_amdgcn_mfma_f32_16x16x32_bf16(a[mi], bv, acc[mi], 0, 0, 0);
        }
    }
    __syncthreads();
    ushort_t* Ys = lds2;   // [64][72]
    #pragma unroll
    for (int mi = 0; mi < 4; ++mi)
        #pragma unroll
        for (int r = 0; r < 4; ++r)
            Ys[(mi * 16 + q * 4 + r) * 72 + w * 16 + la] = f2bits(acc[mi][r]);
    __syncthreads();
    #pragma unroll
    for (int r = 0; r < 2; ++r) {
        int e = t + 256 * r, ml = e >> 3, oct = e & 7;
        us8 v = *(const us8*)(Ys + ml * 72 + oct * 8);
        *(us8*)(adj2T + (size_t)(mt * 64 + ml) * 512 + nc * 64 + oct * 8) = v;
    }
}

// ---------------- K1: FUSED MFMA gated conv + skip conv (+ optional output BN)
// v4: async H staging via gload16 into rotated stride-64 Hs (rot = row + row>>5);
//     out-RMW read prefetched at kernel entry (T14); storeG merged into skip phase.
__global__ __launch_bounds__(256, 4) void k_gs_mfma(
        const ushort_t* __restrict__ h,
        const float* __restrict__ Wf, const float* __restrict__ bfp,
        const float* __restrict__ Wg, const float* __restrict__ bgp,
        const float* __restrict__ Wsk, const float* __restrict__ bsk,
        ushort_t* __restrict__ G, float* __restrict__ out,
        int off, int mode, int storeG,
        const float* __restrict__ og, const float* __restrict__ obb) {
    // Hs 64x64 rot (8192B) | Asf 32x72 (4608B) | Asg 32x72 (4608B) | As2 32x40 (2560B)
    // St float[128][36] (18432B) aliases lds base after all bf16 uses complete.
    __shared__ __align__(16) ushort_t lds[9984];   // 19968 B
    ushort_t* Hs  = lds;           // [64 rows][64], slot = ((l>>3)+row+(row>>5))&7
    ushort_t* Asf = lds + 4096;
    ushort_t* Asg = lds + 6400;
    ushort_t* As2 = lds + 8704;
    __shared__ float bfv[32], bgv[32], bsv[32];
    int t = threadIdx.x;
    int b = blockIdx.x >> 8, n0 = (blockIdx.x & 255) * 2;
    int lane = t & 63, w = t >> 6;
    int ng = w & 1, cg = w >> 1;
    int la = lane & 15, q = lane >> 4;

    // --- async stage H tile (rotated layout via pre-rotated global octet)
    const ushort_t* hb = h + (size_t)(b * 32) * 512 * 64;
    #pragma unroll
    for (int r = 0; r < 2; ++r) {
        int e = t + 256 * r;               // 512 16B-units
        int row = e >> 3, s = e & 7;
        int og_ = ((s - row - (row >> 5)) & 7) * 8;
        gload16(hb + ((size_t)(row >> 1) * 512 + n0 + (row & 1)) * 64 + og_,
                Hs + (size_t)e * 8);
    }
    // --- weights (reg-staged: fp32->bf16 + layout transform)
    {
        int o = t >> 3, k8 = (t & 7) * 8;
        us8 vf, vg;
        #pragma unroll
        for (int i = 0; i < 8; ++i) {
            int k = k8 + i, c = k & 31, tap = k >> 5;
            vf[i] = f2bits(Wf[o * 64 + c * 2 + tap]);
            vg[i] = f2bits(Wg[o * 64 + c * 2 + tap]);
        }
        *(us8*)(Asf + o * 72 + k8) = vf;
        *(us8*)(Asg + o * 72 + k8) = vg;
        if (k8 < 32) {
            us8 vs;
            #pragma unroll
            for (int i = 0; i < 8; ++i) vs[i] = f2bits(Wsk[o * 32 + k8 + i]);
            *(us8*)(As2 + o * 40 + k8) = vs;
        }
        if (t < 32) { bfv[t] = bfp[t]; bgv[t] = bgp[t]; bsv[t] = bsk[t]; }
    }
    // --- T14: prefetch the out-RMW read; consumed at the very end
    float4 oldv[4];
    #pragma unroll
    for (int i = 0; i < 4; ++i) oldv[i] = make_float4(0.f, 0.f, 0.f, 0.f);
    {
        int col = t >> 1, o0 = (t & 1) * 16;
        int nr = col >> 6, l = col & 63;
        if (mode != 0 && l < LOUT_) {
            const float* po = out + ((size_t)(b * LOUT_ + l) * 512 + n0 + nr) * 32 + o0;
            #pragma unroll
            for (int i = 0; i < 4; ++i) oldv[i] = *(const float4*)(po + i * 4);
        }
    }
    __syncthreads();   // drains gload16 (vmcnt) + weight ds_writes

    bf16x8 af[2][2], ag[2][2];
    #pragma unroll
    for (int mt = 0; mt < 2; ++mt)
        #pragma unroll
        for (int ks = 0; ks < 2; ++ks) {
            af[mt][ks] = *(const bf16x8*)(Asf + (mt * 16 + la) * 72 + ks * 32 + q * 8);
            ag[mt][ks] = *(const bf16x8*)(Asg + (mt * 16 + la) * 72 + ks * 32 + q * 8);
        }
    bf16x8 a2[2];
    a2[0] = *(const bf16x8*)(As2 + la * 40 + q * 8);
    a2[1] = *(const bf16x8*)(As2 + (16 + la) * 40 + q * 8);

    f32x4 fa[2][2], ga[2][2];
    #pragma unroll
    for (int mt = 0; mt < 2; ++mt)
        #pragma unroll
        for (int cl = 0; cl < 2; ++cl) { fa[mt][cl] = (f32x4)0.f; ga[mt][cl] = (f32x4)0.f; }
    #pragma unroll
    for (int cl = 0; cl < 2; ++cl) {
        int ct = cg * 2 + cl;
        #pragma unroll
        for (int ks = 0; ks < 2; ++ks) {
            int le = ct * 16 + la + ks;
            bf16x8 bv;
            #pragma unroll
            for (int j = 0; j < 8; ++j) {
                int row = (q * 8 + j) * 2 + ng;
                int slot = ((le >> 3) + row + (row >> 5)) & 7;
                bv[j] = (le < 64) ? (short)Hs[row * 64 + (slot & 7) * 8 + (le & 7)] : (short)0;
            }
            #pragma unroll
            for (int mt = 0; mt < 2; ++mt) {
                fa[mt][cl] = __builtin_amdgcn_mfma_f32_16x16x32_bf16(af[mt][ks], bv, fa[mt][cl], 0, 0, 0);
                ga[mt][cl] = __builtin_amdgcn_mfma_f32_16x16x32_bf16(ag[mt][ks], bv, ga[mt][cl], 0, 0, 0);
            }
        }
    }
    __syncthreads();   // all H reads done before act overwrites (col 32 crosses cg waves)

    #pragma unroll
    for (int mt = 0; mt < 2; ++mt)
        #pragma unroll
        for (int cl = 0; cl < 2; ++cl)
            #pragma unroll
            for (int r = 0; r < 4; ++r) {
                int o = mt * 16 + q * 4 + r;
                float fv = fa[mt][cl][r] + bfv[o];
                float gv = ga[mt][cl][r] + bgv[o];
                float ef = __expf(2.f * fv);
                float act = (1.f - 2.f / (ef + 1.f)) * (1.f / (1.f + __expf(-gv)));
                int l = (cg * 2 + cl) * 16 + la;
                int row = o * 2 + ng;
                int slot = ((l >> 3) + row + (row >> 5)) & 7;
                Hs[row * 64 + slot * 8 + (l & 7)] = f2bits(act);
            }
    __syncthreads();   // gated tile complete

    // --- merged phase: storeG (read-only on Hs) + skip MFMA (read-only on Hs)
    if (storeG) {
        #pragma unroll
        for (int r = 0; r < 2; ++r) {
            int e = t + 256 * r;
            int row = e >> 3, s = e & 7;
            int og_ = (s - row - (row >> 5)) & 7;
            us8 v = *(const us8*)(Hs + (size_t)e * 8);
            *(us8*)(G + ((size_t)(b * 32 + (row >> 1)) * 512 + n0 + (row & 1)) * 64 + og_ * 8) = v;
        }
    }
    f32x4 sa[2][2];
    #pragma unroll
    for (int mt = 0; mt < 2; ++mt)
        #pragma unroll
        for (int cl = 0; cl < 2; ++cl) sa[mt][cl] = (f32x4)0.f;
    #pragma unroll
    for (int cl = 0; cl < 2; ++cl) {
        int le = (cg * 2 + cl) * 16 + la + off;
        bf16x8 bv;
        #pragma unroll
        for (int j = 0; j < 8; ++j) {
            int row = (q * 8 + j) * 2 + ng;
            int slot = ((le >> 3) + row + (row >> 5)) & 7;
            bv[j] = (le < 64) ? (short)Hs[row * 64 + (slot & 7) * 8 + (le & 7)] : (short)0;
        }
        sa[0][cl] = __builtin_amdgcn_mfma_f32_16x16x32_bf16(a2[0], bv, sa[0][cl], 0, 0, 0);
        sa[1][cl] = __builtin_amdgcn_mfma_f32_16x16x32_bf16(a2[1], bv, sa[1][cl], 0, 0, 0);
    }
    __syncthreads();   // Hs/As2 dead -> St overlays lds

    float* St = (float*)lds;               // [128 cols][36]; col = ng*64 + l
    const float rbn = rsqrtf(1.f + 1e-5f);
    #pragma unroll
    for (int mt = 0; mt < 2; ++mt)
        #pragma unroll
        for (int cl = 0; cl < 2; ++cl) {
            int col = ng * 64 + (cg * 2 + cl) * 16 + la;
            int ob = mt * 16 + q * 4;
            float4 sv = make_float4(sa[mt][cl][0] + bsv[ob],
                                    sa[mt][cl][1] + bsv[ob + 1],
                                    sa[mt][cl][2] + bsv[ob + 2],
                                    sa[mt][cl][3] + bsv[ob + 3]);
            *(float4*)(St + col * 36 + ob) = sv;
        }
    __syncthreads();
    {
        int col = t >> 1, o0 = (t & 1) * 16;
        int nr = col >> 6, l = col & 63;
        if (l < LOUT_) {
            float* po = out + ((size_t)(b * LOUT_ + l) * 512 + n0 + nr) * 32 + o0;
            #pragma unroll
            for (int i = 0; i < 4; ++i) {
                float4 s = *(float4*)(St + col * 36 + o0 + i * 4);
                if (mode == 0) {
                    *(float4*)(po + i * 4) = s;
                } else {
                    float4 vv = make_float4(oldv[i].x + s.x, oldv[i].y + s.y,
                                            oldv[i].z + s.z, oldv[i].w + s.w);
                    if (mode == 2) {
                        int ob = o0 + i * 4;
                        vv.x = vv.x * (og[ob] * rbn) + obb[ob];
                        vv.y = vv.y * (og[ob + 1] * rbn) + obb[ob + 1];
                        vv.z = vv.z * (og[ob + 2] * rbn) + obb[ob + 2];
                        vv.w = vv.w * (og[ob + 3] * rbn) + obb[ob + 3];
                    }
                    *(float4*)(po + i * 4) = vv;
                }
            }
        }
    }
}

// ---------------- K3: dual MFMA diffusion: x1 = G.adj, x2 = G.adj2 in one pass
// v5: = v3 + uniform A-swizzle. At 128B row stride, a granule's bank group is
//     (granule mod 8) independent of the row; full-row rotation bl=(ks*4+q+m)&7
//     is exactly uniform (8 lanes/group = b128 minimum). Session-best config.
__global__ __launch_bounds__(256, 2) void k_diffuse2(
        const ushort_t* __restrict__ X, const ushort_t* __restrict__ adjT,
        const ushort_t* __restrict__ adj2T,
        ushort_t* __restrict__ Y1, ushort_t* __restrict__ Y2) {
    __shared__ __align__(16) ushort_t lds[32768];  // 64KB: 2 x (As1 4K | As2 4K | Xs 8K ushorts)
    int cp = blockIdx.x & 15;          // c-pair (2 channels)
    int mt = (blockIdx.x >> 4) & 7;
    int b  = blockIdx.x >> 7;
    int t  = threadIdx.x;
    int lane = t & 63, w = t >> 6;
    int c_loc = w & 1, lh = w >> 1;
    int m0 = mt * 64;
    int la = lane & 15, q = lane >> 4;
    int p_ = la & 1;                                   // column parity within lane pair
    u32 sel = p_ ? 0x07060302u : 0x05040100u;          // v_perm: pick hi16s / lo16s
    const ushort_t* Xb = X + (size_t)(b * 32 + cp * 2) * 512 * 64;
    f32x4 acc1[4][2], acc2[4][2];
    #pragma unroll
    for (int mi = 0; mi < 4; ++mi)
        #pragma unroll
        for (int li = 0; li < 2; ++li) { acc1[mi][li] = (f32x4)0.f; acc2[mi][li] = (f32x4)0.f; }

    union U { u32 u[4]; bf16x8 v; };

    // stage one 64-wide n-tile into buffer bb (linear LDS dest, pre-swizzled global src)
    auto STAGE = [&](int n0, ushort_t* bb) {
        ushort_t* As1b = bb;
        ushort_t* As2b = bb + 4096;
        ushort_t* Xsb  = bb + 8192;
        #pragma unroll
        for (int r = 0; r < 2; ++r) {
            int e = t + 256 * r, ml = e >> 3, s = e & 7;
            int og = ((s - ml) & 7) * 8;               // full-row rotation (uniform banks)
            gload16(adjT  + (size_t)(m0 + ml) * 512 + n0 + og, As1b + (size_t)e * 8);
            gload16(adj2T + (size_t)(m0 + ml) * 512 + n0 + og, As2b + (size_t)e * 8);
        }
        #pragma unroll
        for (int r = 0; r < 4; ++r) {
            int e = t + 256 * r;
            int cl = e >> 9, nl = (e >> 3) & 63, s = e & 7;
            int og = ((s - nl - (nl >> 3)) & 7) * 8;   // per-row rotation
            gload16(Xb + ((size_t)cl * 512 + n0 + nl) * 64 + og, Xsb + (size_t)e * 8);
        }
    };

    STAGE(0, lds);
    __syncthreads();                       // drain prologue loads

    for (int it = 0; it < 8; ++it) {
        ushort_t* cur = lds + (it & 1) * 16384;
        if (it < 7) STAGE((it + 1) * 64, lds + ((it + 1) & 1) * 16384);
        ushort_t* As1 = cur;
        ushort_t* As2 = cur + 4096;
        ushort_t* Xs  = cur + 8192;
        const ushort_t* xc = Xs + c_loc * 4096;
        #pragma unroll
        for (int ks = 0; ks < 2; ++ks) {
            bf16x8 a1[4], a2v[4];
            #pragma unroll
            for (int mi = 0; mi < 4; ++mi) {
                int m = mi * 16 + la;
                int bl = (ks * 4 + q + m) & 7;         // matches full-row rotation
                a1[mi]  = *(const bf16x8*)(As1 + m * 64 + bl * 8);
                a2v[mi] = *(const bf16x8*)(As2 + m * 64 + bl * 8);
            }
            bf16x8 bb[2];
            #pragma unroll
            for (int li = 0; li < 2; ++li) {
                int l2 = lh * 32 + li * 16 + (la & ~1);
                int r0 = ks * 32 + q * 8 + p_ * 4;
                int brot = ((l2 >> 3) + p_ * 4 + ks * 4 + q) & 7;  // slot for jj=0
                u32 o0 = *(const u32*)(xc + (r0 + 0) * 64 + (((brot + 0) & 7) << 3) + (l2 & 7));
                u32 o1 = *(const u32*)(xc + (r0 + 1) * 64 + (((brot + 1) & 7) << 3) + (l2 & 7));
                u32 o2 = *(const u32*)(xc + (r0 + 2) * 64 + (((brot + 2) & 7) << 3) + (l2 & 7));
                u32 o3 = *(const u32*)(xc + (r0 + 3) * 64 + (((brot + 3) & 7) << 3) + (l2 & 7));
                u32 s0 = swap1(o0), s1 = swap1(o1), s2 = swap1(o2), s3 = swap1(o3);
                u32 lo0 = p_ ? s0 : o0, lo1 = p_ ? s1 : o1;
                u32 lo2 = p_ ? s2 : o2, lo3 = p_ ? s3 : o3;
                u32 hi0 = p_ ? o0 : s0, hi1 = p_ ? o1 : s1;
                u32 hi2 = p_ ? o2 : s2, hi3 = p_ ? o3 : s3;
                U u;
                u.u[0] = __builtin_amdgcn_perm(lo1, lo0, sel);   // rows j=0,1
                u.u[1] = __builtin_amdgcn_perm(lo3, lo2, sel);   // rows j=2,3
                u.u[2] = __builtin_amdgcn_perm(hi1, hi0, sel);   // rows j=4,5
                u.u[3] = __builtin_amdgcn_perm(hi3, hi2, sel);   // rows j=6,7
                bb[li] = u.v;
            }
            #pragma unroll
            for (int mi = 0; mi < 4; ++mi)
                #pragma unroll
                for (int li = 0; li < 2; ++li) {
                    acc1[mi][li] = __builtin_amdgcn_mfma_f32_16x16x32_bf16(a1[mi],  bb[li], acc1[mi][li], 0, 0, 0);
                    acc2[mi][li] = __builtin_amdgcn_mfma_f32_16x16x32_bf16(a2v[mi], bb[li], acc2[mi][li], 0, 0, 0);
                }
        }
        __syncthreads();   // drains vmcnt(0): next tile landed; cur free for overwrite
    }

    ushort_t* Ys = lds;                            // [2][64][72]
    #pragma unroll
    for (int pass = 0; pass < 2; ++pass) {
        __syncthreads();
        f32x4 (*src)[2] = pass ? acc2 : acc1;
        #pragma unroll
        for (int mi = 0; mi < 4; ++mi)
            #pragma unroll
            for (int li = 0; li < 2; ++li)
                #pragma unroll
                for (int r = 0; r < 4; ++r) {
                    int row = mi * 16 + q * 4 + r;
                    int col = lh * 32 + li * 16 + la;
                    Ys[c_loc * 4608 + row * 72 + col] = f2bits(src[mi][li][r]);
                }
        __syncthreads();
        ushort_t* Yo = pass ? Y2 : Y1;
        int c = t >> 7, mrem = t & 127;
        int m = mrem >> 1, lq = mrem & 1;
        #pragma unroll
        for (int r = 0; r < 4; ++r) {
            int l0 = lq * 32 + r * 8;
            us8 v = *(const us8*)(Ys + c * 4608 + m * 72 + l0);
            *(us8*)(Yo + ((size_t)(b * 32 + cp * 2 + c) * 512 + m0 + m) * 64 + l0) = v;
        }
    }
}

// ---------------- K4: MFMA graph-conv(96->32) + gcBN + residual + BN, in place over G.
// v2: 2-node blocks (grid 2048); rotated stride-64 cat staged via global_load_lds
//     (inverse-rotated global source); B-fragments via dword-pair + DPP + v_perm.
__global__ __launch_bounds__(256, 4) void k_gc3_mfma(
        ushort_t* __restrict__ G, const ushort_t* __restrict__ X1,
        const ushort_t* __restrict__ X2, const ushort_t* __restrict__ hres,
        const float* __restrict__ Wgc, const float* __restrict__ bgc,
        const float* __restrict__ gg, const float* __restrict__ gb,
        const float* __restrict__ bg2, const float* __restrict__ bb2) {
    __shared__ __align__(16) ushort_t cat[192 * 64];   // rows k*2+nr, rotated; reused as out tile
    __shared__ __align__(16) ushort_t hr[64 * 64];     // hres rows o*2+nr, plain
    __shared__ __align__(16) ushort_t Aw[32 * 104];    // Wgc bf16 [o][96]
    __shared__ float prm[5][32];                       // bgc, gg, gb, bg2, bb2
    int t = threadIdx.x;
    int b = blockIdx.x >> 8, n0 = (blockIdx.x & 255) * 2;
    int lane = t & 63, w = t >> 6;
    int ng = w & 1, cg = w >> 1;
    int la = lane & 15, q = lane >> 4;
    int p_ = la & 1;
    u32 sel = p_ ? 0x07060302u : 0x05040100u;

    // stage cat: 192 rows x 64, gload16 with inverse rotation on global octet
    #pragma unroll
    for (int r = 0; r < 6; ++r) {
        int e = t + 256 * r;
        int row = e >> 3, s = e & 7;
        int k = row >> 1, nr = row & 1;
        int rot = k + (k >> 3);
        int og = ((s - rot) & 7) * 8;
        const ushort_t* src = (k < 32) ? G : ((k < 64) ? X1 : X2);
        gload16(src + ((size_t)(b * 32 + (k & 31)) * 512 + n0 + nr) * 64 + og,
                cat + (size_t)e * 8);
    }
    // stage hres: 64 rows x 64, linear
    #pragma unroll
    for (int r = 0; r < 2; ++r) {
        int e = t + 256 * r;
        int row = e >> 3, oct = e & 7;
        gload16(hres + ((size_t)(b * 32 + (row >> 1)) * 512 + n0 + (row & 1)) * 64 + oct * 8,
                hr + (size_t)e * 8);
    }
    for (int e = t; e < 384; e += 256) {           // stage weights fp32->bf16
        int o = e / 12, oct = e % 12;
        us8 v;
        #pragma unroll
        for (int i = 0; i < 8; ++i) v[i] = f2bits(Wgc[o * 96 + oct * 8 + i]);
        *(us8*)(Aw + o * 104 + oct * 8) = v;
    }
    if (t < 32) {
        prm[0][t] = bgc[t]; prm[1][t] = gg[t]; prm[2][t] = gb[t];
        prm[3][t] = bg2[t]; prm[4][t] = bb2[t];
    }
    __syncthreads();   // drains vmcnt(0) + lgkmcnt(0)

    bf16x8 a[2][3];
    #pragma unroll
    for (int mt = 0; mt < 2; ++mt)
        #pragma unroll
        for (int ks = 0; ks < 3; ++ks)
            a[mt][ks] = *(const bf16x8*)(Aw + (mt * 16 + la) * 104 + ks * 32 + q * 8);

    union U { u32 u[4]; bf16x8 v; };
    f32x4 acc[2][2];
    #pragma unroll
    for (int mt = 0; mt < 2; ++mt)
        #pragma unroll
        for (int cl = 0; cl < 2; ++cl) acc[mt][cl] = (f32x4)0.f;
    #pragma unroll
    for (int cl = 0; cl < 2; ++cl) {
        int l2 = (cg * 2 + cl) * 16 + (la & ~1);
        #pragma unroll
        for (int ks = 0; ks < 3; ++ks) {
            // lane handles j = p_*4 + jj (jj=0..3); row(j) = 2*(ks*32+q*8+j) + ng
            int rb = (ks * 64 + q * 16 + p_ * 8 + ng);
            int brot = ((l2 >> 3) + p_ * 4 + ks * 4 + q) & 7;
            u32 o0 = *(const u32*)(cat + (rb + 0) * 64 + (((brot + 0) & 7) << 3) + (l2 & 7));
            u32 o1 = *(const u32*)(cat + (rb + 2) * 64 + (((brot + 1) & 7) << 3) + (l2 & 7));
            u32 o2 = *(const u32*)(cat + (rb + 4) * 64 + (((brot + 2) & 7) << 3) + (l2 & 7));
            u32 o3 = *(const u32*)(cat + (rb + 6) * 64 + (((brot + 3) & 7) << 3) + (l2 & 7));
            u32 s0 = swap1(o0), s1 = swap1(o1), s2 = swap1(o2), s3 = swap1(o3);
            u32 lo0 = p_ ? s0 : o0, lo1 = p_ ? s1 : o1;
            u32 lo2 = p_ ? s2 : o2, lo3 = p_ ? s3 : o3;
            u32 hi0 = p_ ? o0 : s0, hi1 = p_ ? o1 : s1;
            u32 hi2 = p_ ? o2 : s2, hi3 = p_ ? o3 : s3;
            U u;
            u.u[0] = __builtin_amdgcn_perm(lo1, lo0, sel);   // j=0,1
            u.u[1] = __builtin_amdgcn_perm(lo3, lo2, sel);   // j=2,3
            u.u[2] = __builtin_amdgcn_perm(hi1, hi0, sel);   // j=4,5
            u.u[3] = __builtin_amdgcn_perm(hi3, hi2, sel);   // j=6,7
            acc[0][cl] = __builtin_amdgcn_mfma_f32_16x16x32_bf16(a[0][ks], u.v, acc[0][cl], 0, 0, 0);
            acc[1][cl] = __builtin_amdgcn_mfma_f32_16x16x32_bf16(a[1][ks], u.v, acc[1][cl], 0, 0, 0);
        }
    }
    __syncthreads();                               // all B reads done; reuse cat as out tile

    const float rbn = rsqrtf(1.f + 1e-5f);
    #pragma unroll
    for (int mt = 0; mt < 2; ++mt)
        #pragma unroll
        for (int cl = 0; cl < 2; ++cl)
            #pragma unroll
            for (int r = 0; r < 4; ++r) {
                int o = mt * 16 + q * 4 + r;
                int l = (cg * 2 + cl) * 16 + la;
                float v = acc[mt][cl][r] + prm[0][o];
                v = v * (prm[1][o] * rbn) + prm[2][o];
                float res = (l < 63) ? bits2f(hr[(o * 2 + ng) * 64 + l + 1]) : 0.f;
                v = (v + res) * (prm[3][o] * rbn) + prm[4][o];
                int row = o * 2 + ng;
                int rot = o + (o >> 3);
                int slot = ((l >> 3) + rot) & 7;
                cat[row * 64 + slot * 8 + (l & 7)] = f2bits(v);
            }
    __syncthreads();
    #pragma unroll
    for (int r = 0; r < 2; ++r) {
        int e = t + 256 * r;
        int row = e >> 3, og = e & 7;
        int o = row >> 1, nr = row & 1;
        int slot = (og + o + (o >> 3)) & 7;
        us8 v = *(const us8*)(cat + row * 64 + slot * 8);
        *(us8*)(G + ((size_t)(b * 32 + o) * 512 + n0 + nr) * 64 + og * 8) = v;
    }
}

extern "C" void kernel_launch(void* const* d_in, const int* in_sizes, int n_in,
                              void* d_out, int out_size, void* d_ws, size_t ws_size,
                              hipStream_t stream) {
    const float* x      = (const float*)d_in[0];
    const float* adj    = (const float*)d_in[1];
    const float* Wstart = (const float*)d_in[2];
    const float* bstart = (const float*)d_in[3];
    const float* Wf     = (const float*)d_in[4];
    const float* bf_    = (const float*)d_in[5];
    const float* Wg     = (const float*)d_in[6];
    const float* bg     = (const float*)d_in[7];
    const float* Wskip  = (const float*)d_in[8];
    const float* bskip  = (const float*)d_in[9];
    const float* Wgc    = (const float*)d_in[10];
    const float* bgc    = (const float*)d_in[11];
    const float* gcbn_g = (const float*)d_in[12];
    const float* gcbn_b = (const float*)d_in[13];
    const float* bn_g   = (const float*)d_in[14];
    const float* bn_b   = (const float*)d_in[15];
    const float* obn_g  = (const float*)d_in[16];
    const float* obn_b  = (const float*)d_in[17];
    float* out = (float*)d_out;

    // 4 bf16 scratch buffers (64 MiB) + adjT + adj2T (512 KiB each)
    ushort_t* P0    = (ushort_t*)d_ws;
    ushort_t* P1    = P0 + BUF_;
    ushort_t* P2    = P1 + BUF_;
    ushort_t* P3    = P2 + BUF_;
    ushort_t* adjT  = P3 + BUF_;
    ushort_t* adj2T = adjT + 512 * 512;

    k_transA<<<64, 256, 0, stream>>>(adj, adjT);
    k_sq<<<64, 256, 0, stream>>>(adjT, adj2T);
    k_start<<<4096, 256, 0, stream>>>(x, Wstart, bstart, P0);

    ushort_t* h  = P0;
    ushort_t* Gb = P1;
    for (int i = 0; i < 3; ++i) {
        int mode = (i == 0) ? 0 : ((i == 2) ? 2 : 1);
        k_gs_mfma<<<2048, 256, 0, stream>>>(h, Wf + i * 2048, bf_ + i * 32,
                                            Wg + i * 2048, bg + i * 32,
                                            Wskip + i * 1024, bskip + i * 32,
                                            Gb, out, 2 - i, mode, (i < 2) ? 1 : 0,
                                            obn_g, obn_b);
        if (i == 2) break;
        k_diffuse2<<<1024, 256, 0, stream>>>(Gb, adjT, adj2T, P2, P3);  // x1, x2
        k_gc3_mfma<<<2048, 256, 0, stream>>>(Gb, P2, P3, h,
                                             Wgc + i * 3072, bgc + i * 32,
                                             gcbn_g + i * 32, gcbn_b + i * 32,
                                             bn_g + i * 32, bn_b + i * 32);
        ushort_t* tmp = h; h = Gb; Gb = tmp;   // new h lives where G was
    }
}